// Round 1
// baseline (1042.341 us; speedup 1.0000x reference)
//
#include <hip/hip_runtime.h>
#include <hip/hip_bf16.h>
#include <math.h>

// Problem constants
#define BB 512
#define NN 128
#define FF 128
#define KK 4

// ---------------------------------------------------------------------------
// D[b,i] = 1 / (sum_{j,k} E[b,i,j,k] + 4)   -- one wave per row of 512 floats
// ---------------------------------------------------------------------------
__global__ __launch_bounds__(256) void k_degree(const float* __restrict__ E,
                                                float* __restrict__ Dout) {
  int wave = threadIdx.x >> 6;
  int lane = threadIdx.x & 63;
  int row  = blockIdx.x * 4 + wave;            // [0, BB*NN)
  const float* p = E + (size_t)row * 512 + lane * 8;
  float4 a = *(const float4*)p;
  float4 b = *(const float4*)(p + 4);
  float s = a.x + a.y + a.z + a.w + b.x + b.y + b.z + b.w;
  #pragma unroll
  for (int off = 32; off > 0; off >>= 1) s += __shfl_down(s, off, 64);
  if (lane == 0) Dout[row] = 1.0f / (s + 4.0f);
}

// ---------------------------------------------------------------------------
// RWt[m][k][n] = RW[m][n][k]   (65536 elements per layer)
// ---------------------------------------------------------------------------
__global__ __launch_bounds__(256) void k_rwt(const float* __restrict__ RW,
                                             float* __restrict__ RWt) {
  int idx = blockIdx.x * 256 + threadIdx.x;    // = m*512 + k*128 + n
  int n = idx & 127;
  int k = (idx >> 7) & 3;
  int m = idx >> 9;
  RWt[idx] = RW[m * 512 + n * 4 + k];
}

// ---------------------------------------------------------------------------
// G-GEMM: per b, [G | S] = H_b @ [RWt | SW]
//   grid (5, B); tile t<4 -> G columns k=t; t==4 -> S
//   classic 128x128 tile, BK=16, 256 threads, 8x8 per thread
// ---------------------------------------------------------------------------
__global__ __launch_bounds__(256) void k_gemm_g(
    const float* __restrict__ Hin,   // [B][128][128]
    const float* __restrict__ RWt,   // [128][512]   (m, k*128+n)
    const float* __restrict__ SW,    // [128][128]
    float* __restrict__ G,           // [B][512][128]  ((j,k), n)
    float* __restrict__ S)           // [B][128][128]
{
  const int t = blockIdx.x;          // 0..4
  const int b = blockIdx.y;
  const float* A  = Hin + (size_t)b * 16384;           // [j][m], lda=128
  const float* Bm = (t < 4) ? (RWt + t * 128) : SW;    // [m][c]
  const int ldb   = (t < 4) ? 512 : 128;

  __shared__ float As[16][132];   // transposed A tile: As[k][j]
  __shared__ float Bs[16][132];   // Bs[k][c]

  const int tid = threadIdx.x;
  const int tr = tid >> 4;   // 0..15, output row group
  const int tc = tid & 15;   // 0..15, output col group

  float acc[8][8] = {};

  for (int k0 = 0; k0 < 128; k0 += 16) {
    #pragma unroll
    for (int p = 0; p < 2; ++p) {
      int f4 = p * 256 + tid;
      int j  = f4 >> 2;
      int m4 = (f4 & 3) * 4;
      float4 v = *(const float4*)(A + j * 128 + k0 + m4);
      As[m4 + 0][j] = v.x; As[m4 + 1][j] = v.y;
      As[m4 + 2][j] = v.z; As[m4 + 3][j] = v.w;
    }
    #pragma unroll
    for (int p = 0; p < 2; ++p) {
      int f4 = p * 256 + tid;
      int m  = f4 >> 5;
      int c  = (f4 & 31) * 4;
      *(float4*)(&Bs[m][c]) = *(const float4*)(Bm + (k0 + m) * ldb + c);
    }
    __syncthreads();
    #pragma unroll
    for (int kk = 0; kk < 16; ++kk) {
      float ra[8], rb[8];
      #pragma unroll
      for (int i = 0; i < 8; ++i) ra[i] = As[kk][tr * 8 + i];
      #pragma unroll
      for (int i = 0; i < 8; ++i) rb[i] = Bs[kk][tc * 8 + i];
      #pragma unroll
      for (int i = 0; i < 8; ++i)
        #pragma unroll
        for (int jx = 0; jx < 8; ++jx)
          acc[i][jx] = fmaf(ra[i], rb[jx], acc[i][jx]);
    }
    __syncthreads();
  }

  float* out; int ldc;
  if (t < 4) { out = G + (size_t)b * 65536 + t * 128; ldc = 512; }
  else       { out = S + (size_t)b * 16384;           ldc = 128; }
  #pragma unroll
  for (int i = 0; i < 8; ++i) {
    int j = tr * 8 + i;
    #pragma unroll
    for (int jx = 0; jx < 8; jx += 4) {
      float4 v = make_float4(acc[i][jx], acc[i][jx+1], acc[i][jx+2], acc[i][jx+3]);
      *(float4*)(out + j * ldc + tc * 8 + jx) = v;
    }
  }
}

// ---------------------------------------------------------------------------
// E-GEMM: per b, msg = E_b @ G_b  (128x128 out, K=512), fused epilogue:
//   Hout = sigmoid(msg * D[b,i] + S[b,i,n])
// ---------------------------------------------------------------------------
__global__ __launch_bounds__(256) void k_gemm_e(
    const float* __restrict__ E,    // [B][128][512]
    const float* __restrict__ G,    // [B][512][128]
    const float* __restrict__ S,    // [B][128][128]
    const float* __restrict__ Dv,   // [B][128]
    float* __restrict__ Hout)       // [B][128][128]
{
  const int b = blockIdx.x;
  const float* A  = E + (size_t)b * 65536;   // [i][p], lda=512
  const float* Bm = G + (size_t)b * 65536;   // [p][n], ldb=128

  __shared__ float As[16][132];
  __shared__ float Bs[16][132];

  const int tid = threadIdx.x;
  const int tr = tid >> 4;
  const int tc = tid & 15;

  float acc[8][8] = {};

  for (int k0 = 0; k0 < 512; k0 += 16) {
    #pragma unroll
    for (int p = 0; p < 2; ++p) {
      int f4 = p * 256 + tid;
      int i  = f4 >> 2;
      int m4 = (f4 & 3) * 4;
      float4 v = *(const float4*)(A + i * 512 + k0 + m4);
      As[m4 + 0][i] = v.x; As[m4 + 1][i] = v.y;
      As[m4 + 2][i] = v.z; As[m4 + 3][i] = v.w;
    }
    #pragma unroll
    for (int p = 0; p < 2; ++p) {
      int f4 = p * 256 + tid;
      int m  = f4 >> 5;
      int c  = (f4 & 31) * 4;
      *(float4*)(&Bs[m][c]) = *(const float4*)(Bm + (k0 + m) * 128 + c);
    }
    __syncthreads();
    #pragma unroll
    for (int kk = 0; kk < 16; ++kk) {
      float ra[8], rb[8];
      #pragma unroll
      for (int i = 0; i < 8; ++i) ra[i] = As[kk][tr * 8 + i];
      #pragma unroll
      for (int i = 0; i < 8; ++i) rb[i] = Bs[kk][tc * 8 + i];
      #pragma unroll
      for (int i = 0; i < 8; ++i)
        #pragma unroll
        for (int jx = 0; jx < 8; ++jx)
          acc[i][jx] = fmaf(ra[i], rb[jx], acc[i][jx]);
    }
    __syncthreads();
  }

  const float* Srow = S + (size_t)b * 16384;
  float* Orow = Hout + (size_t)b * 16384;
  #pragma unroll
  for (int i = 0; i < 8; ++i) {
    int r = tr * 8 + i;
    float d = Dv[b * 128 + r];
    #pragma unroll
    for (int jx = 0; jx < 8; ++jx) {
      int c = tc * 8 + jx;
      float v = fmaf(acc[i][jx], d, Srow[r * 128 + c]);
      Orow[r * 128 + c] = 1.0f / (1.0f + __expf(-v));
    }
  }
}

// ---------------------------------------------------------------------------
// MLP head: per row r: h=LeakyReLU(H[r]@W1+b1,0.1); s=sigmoid(h@W2+b2);
// block-reduce then one atomicAdd per block into sumOut.
// ---------------------------------------------------------------------------
__global__ __launch_bounds__(256) void k_mlp(
    const float* __restrict__ H,   // [B*N][128]
    const float* __restrict__ W1,  // [128][20]
    const float* __restrict__ b1,  // [20]
    const float* __restrict__ W2,  // [20]
    const float* __restrict__ b2,  // [1]
    float* __restrict__ sumOut)
{
  __shared__ float W1s[128 * 20];
  __shared__ float b1s[20], W2s[20];
  __shared__ float red[256];
  for (int i = threadIdx.x; i < 2560; i += 256) W1s[i] = W1[i];
  if (threadIdx.x < 20) { b1s[threadIdx.x] = b1[threadIdx.x]; W2s[threadIdx.x] = W2[threadIdx.x]; }
  __syncthreads();

  int row = blockIdx.x * 256 + threadIdx.x;
  float h[20];
  #pragma unroll
  for (int j = 0; j < 20; ++j) h[j] = b1s[j];
  const float* hr = H + (size_t)row * 128;
  for (int m = 0; m < 128; ++m) {
    float x = hr[m];
    #pragma unroll
    for (int j = 0; j < 20; ++j) h[j] = fmaf(x, W1s[m * 20 + j], h[j]);
  }
  float v = b2[0];
  #pragma unroll
  for (int j = 0; j < 20; ++j) {
    float t = h[j];
    t = fmaxf(t, 0.1f * t);     // LeakyReLU(0.1)
    v = fmaf(t, W2s[j], v);
  }
  float s = 1.0f / (1.0f + __expf(-v));

  red[threadIdx.x] = s;
  __syncthreads();
  #pragma unroll
  for (int off = 128; off > 0; off >>= 1) {
    if (threadIdx.x < off) red[threadIdx.x] += red[threadIdx.x + off];
    __syncthreads();
  }
  if (threadIdx.x == 0) atomicAdd(sumOut, red[0]);
}

__global__ void k_final(const float* __restrict__ sum, float* __restrict__ out) {
  out[0] = sum[0] * (1.0f / 65536.0f);
}

// ---------------------------------------------------------------------------
extern "C" void kernel_launch(void* const* d_in, const int* in_sizes, int n_in,
                              void* d_out, int out_size, void* d_ws, size_t ws_size,
                              hipStream_t stream) {
  const float* H   = (const float*)d_in[0];
  const float* E   = (const float*)d_in[1];
  const float* RW1 = (const float*)d_in[2];
  const float* SW1 = (const float*)d_in[3];
  const float* RW2 = (const float*)d_in[4];
  const float* SW2 = (const float*)d_in[5];
  const float* RW3 = (const float*)d_in[6];
  const float* SW3 = (const float*)d_in[7];
  const float* W1  = (const float*)d_in[8];
  const float* b1  = (const float*)d_in[9];
  const float* W2  = (const float*)d_in[10];
  const float* b2  = (const float*)d_in[11];
  float* out = (float*)d_out;

  float* w = (float*)d_ws;
  float* wsD   = w;                        // 65536
  float* wsRWt = wsD + 65536;              // 3 * 65536
  float* wsG   = wsRWt + 3 * 65536;        // 512*65536 = 33554432
  float* wsS   = wsG + (size_t)512 * 65536;   // 512*16384
  float* wsHa  = wsS + (size_t)512 * 16384;   // 512*16384
  float* wsHb  = wsHa + (size_t)512 * 16384;  // 512*16384
  float* wsSum = wsHb + (size_t)512 * 16384;  // 1

  // degree norm
  k_degree<<<BB * NN / 4, 256, 0, stream>>>(E, wsD);
  // RW transposes
  k_rwt<<<256, 256, 0, stream>>>(RW1, wsRWt);
  k_rwt<<<256, 256, 0, stream>>>(RW2, wsRWt + 65536);
  k_rwt<<<256, 256, 0, stream>>>(RW3, wsRWt + 131072);
  // zero the scalar accumulator (ws is poisoned 0xAA before every launch)
  hipMemsetAsync(wsSum, 0, sizeof(float), stream);

  // layer 1: H(d_in) -> wsHa
  k_gemm_g<<<dim3(5, BB), 256, 0, stream>>>(H, wsRWt, SW1, wsG, wsS);
  k_gemm_e<<<BB, 256, 0, stream>>>(E, wsG, wsS, wsD, wsHa);
  // layer 2: wsHa -> wsHb
  k_gemm_g<<<dim3(5, BB), 256, 0, stream>>>(wsHa, wsRWt + 65536, SW2, wsG, wsS);
  k_gemm_e<<<BB, 256, 0, stream>>>(E, wsG, wsS, wsD, wsHb);
  // layer 3: wsHb -> wsHa
  k_gemm_g<<<dim3(5, BB), 256, 0, stream>>>(wsHb, wsRWt + 131072, SW3, wsG, wsS);
  k_gemm_e<<<BB, 256, 0, stream>>>(E, wsG, wsS, wsD, wsHa);

  // MLP head + mean
  k_mlp<<<BB * NN / 256, 256, 0, stream>>>(wsHa, W1, b1, W2, b2, wsSum);
  k_final<<<1, 1, 0, stream>>>(wsSum, out);
}

// Round 2
// 494.169 us; speedup vs baseline: 2.1093x; 2.1093x over previous
//
#include <hip/hip_runtime.h>
#include <math.h>

#define BB 512
#define NN 128
#define FF 128
#define KK 4

typedef __attribute__((ext_vector_type(8))) short bf16x8;
typedef __attribute__((ext_vector_type(4))) float f32x4;

__device__ inline unsigned short f2bf(float x) {
  union { float f; unsigned int u; } v; v.f = x;
  unsigned int r = v.u + 0x7fff + ((v.u >> 16) & 1);   // RNE
  return (unsigned short)(r >> 16);
}
__device__ inline float bf2f(unsigned short h) {
  union { unsigned int u; float f; } v; v.u = ((unsigned int)h) << 16; return v.f;
}

// ---------------------------------------------------------------------------
// E fp32 -> bf16 + degree norm D. One wave per row of 512.
// ---------------------------------------------------------------------------
__global__ __launch_bounds__(256) void k_convE(const float* __restrict__ E,
                                               unsigned short* __restrict__ Eb,
                                               float* __restrict__ Dv) {
  int wave = threadIdx.x >> 6;
  int lane = threadIdx.x & 63;
  int row  = blockIdx.x * 4 + wave;            // [0, BB*NN)
  const float* p = E + (size_t)row * 512 + lane * 8;
  f32x4 a = *(const f32x4*)p;
  f32x4 b = *(const f32x4*)(p + 4);
  float s = a[0] + a[1] + a[2] + a[3] + b[0] + b[1] + b[2] + b[3];
  #pragma unroll
  for (int off = 32; off > 0; off >>= 1) s += __shfl_down(s, off, 64);
  if (lane == 0) Dv[row] = 1.0f / (s + 4.0f);
  union { unsigned short h[8]; f32x4 v; } u;
  u.h[0] = f2bf(a[0]); u.h[1] = f2bf(a[1]); u.h[2] = f2bf(a[2]); u.h[3] = f2bf(a[3]);
  u.h[4] = f2bf(b[0]); u.h[5] = f2bf(b[1]); u.h[6] = f2bf(b[2]); u.h[7] = f2bf(b[3]);
  *(f32x4*)(Eb + (size_t)row * 512 + lane * 8) = u.v;
}

// ---------------------------------------------------------------------------
// H fp32 -> bf16 (8 elems per thread)
// ---------------------------------------------------------------------------
__global__ __launch_bounds__(256) void k_convH(const float* __restrict__ H,
                                               unsigned short* __restrict__ Hb) {
  size_t i = ((size_t)blockIdx.x * 256 + threadIdx.x) * 8;
  f32x4 a = *(const f32x4*)(H + i);
  f32x4 b = *(const f32x4*)(H + i + 4);
  union { unsigned short h[8]; f32x4 v; } u;
  u.h[0] = f2bf(a[0]); u.h[1] = f2bf(a[1]); u.h[2] = f2bf(a[2]); u.h[3] = f2bf(a[3]);
  u.h[4] = f2bf(b[0]); u.h[5] = f2bf(b[1]); u.h[6] = f2bf(b[2]); u.h[7] = f2bf(b[3]);
  *(f32x4*)(Hb + i) = u.v;
}

// ---------------------------------------------------------------------------
// W2[c][m]: c<512 -> RW[m*512+c]  (c = n*4+k);  c>=512 -> SW[m*128+(c-512)]
// 640*128 bf16 per layer
// ---------------------------------------------------------------------------
__global__ __launch_bounds__(256) void k_buildW(const float* __restrict__ RW,
                                                const float* __restrict__ SW,
                                                unsigned short* __restrict__ W2) {
  int idx = blockIdx.x * 256 + threadIdx.x;    // c*128 + m, 81920 total
  int m = idx & 127;
  int c = idx >> 7;
  float v = (c < 512) ? RW[m * 512 + c] : SW[m * 128 + (c - 512)];
  W2[idx] = f2bf(v);
}

// ---------------------------------------------------------------------------
// gemm_g: per b, C[j][c] = Hb_b[j][m] @ W2[c][m]^T   (M=128, N=640, K=128)
// grid (5, B). cb<4 -> scatter to Gt[n][j*4+k]; cb==4 -> St[s][j] fp32.
// ---------------------------------------------------------------------------
__global__ __launch_bounds__(256) void k_gemm_g(
    const unsigned short* __restrict__ Hb,   // [B][128][128]
    const unsigned short* __restrict__ W2,   // [640][128]
    unsigned short* __restrict__ Gt,         // [B][128][512]  (n, j*4+k)
    float* __restrict__ St)                  // [B][128][128]  (s, j)
{
  const int cb = blockIdx.x;                 // 0..4
  const int b  = blockIdx.y;
  const unsigned short* A  = Hb + (size_t)b * 16384;    // [j][m], ld=128
  const unsigned short* Bm = W2 + cb * 128 * 128;       // [c][m], ld=128

  __shared__ unsigned short As[128 * 40];
  __shared__ unsigned short Bs[128 * 40];

  const int tid = threadIdx.x;
  const int w = tid >> 6, l = tid & 63;
  const int wr = w >> 1, wc = w & 1;
  const int lq = l >> 4, lm = l & 15;

  const int srow = tid >> 1;
  const int sch  = (tid & 1) * 16;

  f32x4 acc[4][4] = {};

  for (int k0 = 0; k0 < 128; k0 += 32) {
    f32x4 va0 = *(const f32x4*)(A + srow * 128 + k0 + sch);
    f32x4 va1 = *(const f32x4*)(A + srow * 128 + k0 + sch + 8);
    f32x4 vb0 = *(const f32x4*)(Bm + srow * 128 + k0 + sch);
    f32x4 vb1 = *(const f32x4*)(Bm + srow * 128 + k0 + sch + 8);
    __syncthreads();
    *(f32x4*)(As + srow * 40 + sch)     = va0;
    *(f32x4*)(As + srow * 40 + sch + 8) = va1;
    *(f32x4*)(Bs + srow * 40 + sch)     = vb0;
    *(f32x4*)(Bs + srow * 40 + sch + 8) = vb1;
    __syncthreads();
    bf16x8 fa[4], fb[4];
    #pragma unroll
    for (int f = 0; f < 4; ++f)
      fa[f] = *(const bf16x8*)(As + (wr * 64 + f * 16 + lm) * 40 + lq * 8);
    #pragma unroll
    for (int g = 0; g < 4; ++g)
      fb[g] = *(const bf16x8*)(Bs + (wc * 64 + g * 16 + lm) * 40 + lq * 8);
    #pragma unroll
    for (int f = 0; f < 4; ++f)
      #pragma unroll
      for (int g = 0; g < 4; ++g)
        acc[f][g] = __builtin_amdgcn_mfma_f32_16x16x32_bf16(fa[f], fb[g], acc[f][g], 0, 0, 0);
  }

  const int cbase = cb * 128 + wc * 64;
  if (cb < 4) {
    unsigned short* gt = Gt + (size_t)b * 65536;
    #pragma unroll
    for (int g = 0; g < 4; ++g) {
      int c = cbase + g * 16 + lm;
      int n = c >> 2, kk = c & 3;
      #pragma unroll
      for (int f = 0; f < 4; ++f) {
        int j0 = wr * 64 + f * 16 + lq * 4;
        #pragma unroll
        for (int r = 0; r < 4; ++r)
          gt[n * 512 + (j0 + r) * 4 + kk] = f2bf(acc[f][g][r]);
      }
    }
  } else {
    float* st = St + (size_t)b * 16384;
    #pragma unroll
    for (int g = 0; g < 4; ++g) {
      int s = wc * 64 + g * 16 + lm;
      #pragma unroll
      for (int f = 0; f < 4; ++f) {
        int j0 = wr * 64 + f * 16 + lq * 4;
        *(f32x4*)(st + s * 128 + j0) = acc[f][g];
      }
    }
  }
}

// ---------------------------------------------------------------------------
// gemm_e: per b, msg[i][n] = Eb_b[i][p] @ Gt_b[n][p]^T  (M=128,N=128,K=512)
// epilogue: Hout[i][n] = bf16(sigmoid(msg*D[b,i] + St[n][i]))
// ---------------------------------------------------------------------------
__global__ __launch_bounds__(256) void k_gemm_e(
    const unsigned short* __restrict__ Eb,  // [B][128][512]
    const unsigned short* __restrict__ Gt,  // [B][128][512]
    const float* __restrict__ St,           // [B][128][128] (n, i)
    const float* __restrict__ Dv,           // [B][128]
    unsigned short* __restrict__ Hout)      // [B][128][128] (i, n)
{
  const int b = blockIdx.x;
  const unsigned short* A  = Eb + (size_t)b * 65536;   // [i][p], ld=512
  const unsigned short* Bm = Gt + (size_t)b * 65536;   // [n][p], ld=512

  __shared__ unsigned short As[128 * 40];
  __shared__ unsigned short Bs[128 * 40];

  const int tid = threadIdx.x;
  const int w = tid >> 6, l = tid & 63;
  const int wr = w >> 1, wc = w & 1;
  const int lq = l >> 4, lm = l & 15;

  const int srow = tid >> 1;
  const int sch  = (tid & 1) * 16;

  f32x4 acc[4][4] = {};

  for (int k0 = 0; k0 < 512; k0 += 32) {
    f32x4 va0 = *(const f32x4*)(A + srow * 512 + k0 + sch);
    f32x4 va1 = *(const f32x4*)(A + srow * 512 + k0 + sch + 8);
    f32x4 vb0 = *(const f32x4*)(Bm + srow * 512 + k0 + sch);
    f32x4 vb1 = *(const f32x4*)(Bm + srow * 512 + k0 + sch + 8);
    __syncthreads();
    *(f32x4*)(As + srow * 40 + sch)     = va0;
    *(f32x4*)(As + srow * 40 + sch + 8) = va1;
    *(f32x4*)(Bs + srow * 40 + sch)     = vb0;
    *(f32x4*)(Bs + srow * 40 + sch + 8) = vb1;
    __syncthreads();
    bf16x8 fa[4], fb[4];
    #pragma unroll
    for (int f = 0; f < 4; ++f)
      fa[f] = *(const bf16x8*)(As + (wr * 64 + f * 16 + lm) * 40 + lq * 8);
    #pragma unroll
    for (int g = 0; g < 4; ++g)
      fb[g] = *(const bf16x8*)(Bs + (wc * 64 + g * 16 + lm) * 40 + lq * 8);
    #pragma unroll
    for (int f = 0; f < 4; ++f)
      #pragma unroll
      for (int g = 0; g < 4; ++g)
        acc[f][g] = __builtin_amdgcn_mfma_f32_16x16x32_bf16(fa[f], fb[g], acc[f][g], 0, 0, 0);
  }

  const float* st = St + (size_t)b * 16384;
  const float* dv = Dv + b * 128;
  unsigned short* ho = Hout + (size_t)b * 16384;
  #pragma unroll
  for (int f = 0; f < 4; ++f) {
    int i0 = wr * 64 + f * 16 + lq * 4;
    f32x4 d = *(const f32x4*)(dv + i0);
    #pragma unroll
    for (int g = 0; g < 4; ++g) {
      int n = wc * 64 + g * 16 + lm;
      f32x4 sv = *(const f32x4*)(st + n * 128 + i0);
      #pragma unroll
      for (int r = 0; r < 4; ++r) {
        float v = fmaf(acc[f][g][r], d[r], sv[r]);
        ho[(i0 + r) * 128 + n] = f2bf(1.0f / (1.0f + __expf(-v)));
      }
    }
  }
}

// ---------------------------------------------------------------------------
// MLP head on bf16 H
// ---------------------------------------------------------------------------
__global__ __launch_bounds__(256) void k_mlp(
    const unsigned short* __restrict__ H,   // [B*N][128] bf16
    const float* __restrict__ W1,  // [128][20]
    const float* __restrict__ b1,  // [20]
    const float* __restrict__ W2,  // [20]
    const float* __restrict__ b2,  // [1]
    float* __restrict__ sumOut)
{
  __shared__ float W1s[128 * 20];
  __shared__ float b1s[20], W2s[20];
  __shared__ float red[256];
  for (int i = threadIdx.x; i < 2560; i += 256) W1s[i] = W1[i];
  if (threadIdx.x < 20) { b1s[threadIdx.x] = b1[threadIdx.x]; W2s[threadIdx.x] = W2[threadIdx.x]; }
  __syncthreads();

  int row = blockIdx.x * 256 + threadIdx.x;
  float h[20];
  #pragma unroll
  for (int j = 0; j < 20; ++j) h[j] = b1s[j];
  const unsigned short* hr = H + (size_t)row * 128;
  for (int m8 = 0; m8 < 128; m8 += 8) {
    f32x4 pk = *(const f32x4*)(hr + m8);
    const unsigned short* us = (const unsigned short*)&pk;
    #pragma unroll
    for (int e = 0; e < 8; ++e) {
      float x = bf2f(us[e]);
      #pragma unroll
      for (int j = 0; j < 20; ++j) h[j] = fmaf(x, W1s[(m8 + e) * 20 + j], h[j]);
    }
  }
  float v = b2[0];
  #pragma unroll
  for (int j = 0; j < 20; ++j) {
    float t = h[j];
    t = fmaxf(t, 0.1f * t);
    v = fmaf(t, W2s[j], v);
  }
  float s = 1.0f / (1.0f + __expf(-v));

  red[threadIdx.x] = s;
  __syncthreads();
  #pragma unroll
  for (int off = 128; off > 0; off >>= 1) {
    if (threadIdx.x < off) red[threadIdx.x] += red[threadIdx.x + off];
    __syncthreads();
  }
  if (threadIdx.x == 0) atomicAdd(sumOut, red[0]);
}

__global__ void k_final(const float* __restrict__ sum, float* __restrict__ out) {
  out[0] = sum[0] * (1.0f / 65536.0f);
}

// ---------------------------------------------------------------------------
extern "C" void kernel_launch(void* const* d_in, const int* in_sizes, int n_in,
                              void* d_out, int out_size, void* d_ws, size_t ws_size,
                              hipStream_t stream) {
  const float* H   = (const float*)d_in[0];
  const float* E   = (const float*)d_in[1];
  const float* RW1 = (const float*)d_in[2];
  const float* SW1 = (const float*)d_in[3];
  const float* RW2 = (const float*)d_in[4];
  const float* SW2 = (const float*)d_in[5];
  const float* RW3 = (const float*)d_in[6];
  const float* SW3 = (const float*)d_in[7];
  const float* W1  = (const float*)d_in[8];
  const float* b1  = (const float*)d_in[9];
  const float* W2  = (const float*)d_in[10];
  const float* b2  = (const float*)d_in[11];
  float* out = (float*)d_out;

  char* w = (char*)d_ws;
  float*          wsD   = (float*)w;                     w += 65536 * 4;           // 256 KB
  unsigned short* wsEb  = (unsigned short*)w;            w += (size_t)33554432 * 2; // 67 MB
  unsigned short* wsGt  = (unsigned short*)w;            w += (size_t)33554432 * 2; // 67 MB
  float*          wsSt  = (float*)w;                     w += (size_t)8388608 * 4;  // 33.5 MB
  unsigned short* wsHa  = (unsigned short*)w;            w += (size_t)8388608 * 2;  // 16.8 MB
  unsigned short* wsHb  = (unsigned short*)w;            w += (size_t)8388608 * 2;  // 16.8 MB
  unsigned short* wsW2  = (unsigned short*)w;            w += (size_t)3 * 81920 * 2;
  float*          wsSum = (float*)w;                     w += 256;

  k_convE<<<BB * NN / 4, 256, 0, stream>>>(E, wsEb, wsD);
  k_convH<<<8388608 / (256 * 8), 256, 0, stream>>>(H, wsHa);
  k_buildW<<<320, 256, 0, stream>>>(RW1, SW1, wsW2);
  k_buildW<<<320, 256, 0, stream>>>(RW2, SW2, wsW2 + 81920);
  k_buildW<<<320, 256, 0, stream>>>(RW3, SW3, wsW2 + 163840);
  hipMemsetAsync(wsSum, 0, sizeof(float), stream);

  // layer 1: wsHa -> wsHb
  k_gemm_g<<<dim3(5, BB), 256, 0, stream>>>(wsHa, wsW2, wsGt, wsSt);
  k_gemm_e<<<BB, 256, 0, stream>>>(wsEb, wsGt, wsSt, wsD, wsHb);
  // layer 2: wsHb -> wsHa
  k_gemm_g<<<dim3(5, BB), 256, 0, stream>>>(wsHb, wsW2 + 81920, wsGt, wsSt);
  k_gemm_e<<<BB, 256, 0, stream>>>(wsEb, wsGt, wsSt, wsD, wsHa);
  // layer 3: wsHa -> wsHb
  k_gemm_g<<<dim3(5, BB), 256, 0, stream>>>(wsHa, wsW2 + 163840, wsGt, wsSt);
  k_gemm_e<<<BB, 256, 0, stream>>>(wsEb, wsGt, wsSt, wsD, wsHb);

  k_mlp<<<BB * NN / 256, 256, 0, stream>>>(wsHb, W1, b1, W2, b2, wsSum);
  k_final<<<1, 1, 0, stream>>>(wsSum, out);
}

// Round 3
// 480.542 us; speedup vs baseline: 2.1691x; 1.0284x over previous
//
#include <hip/hip_runtime.h>
#include <math.h>

#define BB 512
#define NN 128
#define FF 128
#define KK 4

typedef __attribute__((ext_vector_type(8))) short bf16x8;
typedef __attribute__((ext_vector_type(4))) float f32x4;

__device__ inline unsigned short f2bf(float x) {
  union { float f; unsigned int u; } v; v.f = x;
  unsigned int r = v.u + 0x7fff + ((v.u >> 16) & 1);   // RNE
  return (unsigned short)(r >> 16);
}
__device__ inline float bf2f(unsigned short h) {
  union { unsigned int u; float f; } v; v.u = ((unsigned int)h) << 16; return v.f;
}

// ---------------------------------------------------------------------------
// E fp32 -> bf16 + degree norm D. One wave per row of 512.
// ---------------------------------------------------------------------------
__global__ __launch_bounds__(256) void k_convE(const float* __restrict__ E,
                                               unsigned short* __restrict__ Eb,
                                               float* __restrict__ Dv) {
  int wave = threadIdx.x >> 6;
  int lane = threadIdx.x & 63;
  int row  = blockIdx.x * 4 + wave;            // [0, BB*NN)
  const float* p = E + (size_t)row * 512 + lane * 8;
  f32x4 a = *(const f32x4*)p;
  f32x4 b = *(const f32x4*)(p + 4);
  float s = a[0] + a[1] + a[2] + a[3] + b[0] + b[1] + b[2] + b[3];
  #pragma unroll
  for (int off = 32; off > 0; off >>= 1) s += __shfl_down(s, off, 64);
  if (lane == 0) Dv[row] = 1.0f / (s + 4.0f);
  union { unsigned short h[8]; f32x4 v; } u;
  u.h[0] = f2bf(a[0]); u.h[1] = f2bf(a[1]); u.h[2] = f2bf(a[2]); u.h[3] = f2bf(a[3]);
  u.h[4] = f2bf(b[0]); u.h[5] = f2bf(b[1]); u.h[6] = f2bf(b[2]); u.h[7] = f2bf(b[3]);
  *(f32x4*)(Eb + (size_t)row * 512 + lane * 8) = u.v;
}

// ---------------------------------------------------------------------------
// H fp32 -> bf16 (8 elems per thread)
// ---------------------------------------------------------------------------
__global__ __launch_bounds__(256) void k_convH(const float* __restrict__ H,
                                               unsigned short* __restrict__ Hb) {
  size_t i = ((size_t)blockIdx.x * 256 + threadIdx.x) * 8;
  f32x4 a = *(const f32x4*)(H + i);
  f32x4 b = *(const f32x4*)(H + i + 4);
  union { unsigned short h[8]; f32x4 v; } u;
  u.h[0] = f2bf(a[0]); u.h[1] = f2bf(a[1]); u.h[2] = f2bf(a[2]); u.h[3] = f2bf(a[3]);
  u.h[4] = f2bf(b[0]); u.h[5] = f2bf(b[1]); u.h[6] = f2bf(b[2]); u.h[7] = f2bf(b[3]);
  *(f32x4*)(Hb + i) = u.v;
}

// ---------------------------------------------------------------------------
// W2[c][m]: c<512 -> RW[m*512+c]  (c = n*4+k);  c>=512 -> SW[m*128+(c-512)]
// ---------------------------------------------------------------------------
__global__ __launch_bounds__(256) void k_buildW(const float* __restrict__ RW,
                                                const float* __restrict__ SW,
                                                unsigned short* __restrict__ W2) {
  int idx = blockIdx.x * 256 + threadIdx.x;    // c*128 + m, 81920 total
  int m = idx & 127;
  int c = idx >> 7;
  float v = (c < 512) ? RW[m * 512 + c] : SW[m * 128 + (c - 512)];
  W2[idx] = f2bf(v);
}

// ---------------------------------------------------------------------------
// Fused RGCN layer, one block per graph b (grid = 512, 256 threads = 4 waves).
//
//   phase 1a (per j-half h): Gt[c'=(n,k)][j] = sum_m W2[c'][m] * Hin[j][m]
//       -> stored transposed+packed into LDS Gs[n][p' = (j-h*64)*4+k]
//       (MFMA with A=W2-rows, B=H-cols: lane's 4 C-regs are k=0..3 at fixed
//        (n,j) -> one 8B LDS write in exactly phase-2's B-fragment layout)
//   phase 2  (per h): macc[i][n] += Eb[i][p] @ Gs[n][p']  (K=256 per half)
//   phase 1b: sacc[j][s] = Hin @ SW  (same quadrant mapping as phase 2
//       -> fragments align 1:1 with macc; S never leaves registers)
//   epilogue: Hout[i][n] = bf16(sigmoid(macc*D[i] + sacc))
//
// All A/B fragments load DIRECT from global (quad lanes form 64B lines);
// LDS holds only Gs: 128*264*2 = 67.6 KB -> 2 blocks/CU.
// ---------------------------------------------------------------------------
#define GS_PITCH 264

__global__ __launch_bounds__(256, 2) void k_layer(
    const unsigned short* __restrict__ Eb,   // [B][128][512]
    const unsigned short* __restrict__ Hin,  // [B][128][128]
    const unsigned short* __restrict__ W2L,  // [640][128]
    const float* __restrict__ Dv,            // [B][128]
    unsigned short* __restrict__ Hout)       // [B][128][128]
{
  __shared__ unsigned short Gs[128 * GS_PITCH];

  const int b = blockIdx.x;
  const unsigned short* E_b = Eb  + (size_t)b * 65536;
  const unsigned short* H_b = Hin + (size_t)b * 16384;

  const int tid = threadIdx.x;
  const int w = tid >> 6, l = tid & 63;
  const int wr = w >> 1, wc = w & 1;
  const int lq = l >> 4, lm = l & 15;

  f32x4 macc[4][4] = {};

  #pragma unroll
  for (int h = 0; h < 2; ++h) {
    __syncthreads();   // Gs safe to overwrite (prev half's readers done)

    // ---- phase 1a: fill Gs for j in [h*64, h*64+64) ----
    #pragma unroll
    for (int cb = 0; cb < 4; ++cb) {
      f32x4 gacc[4][2] = {};
      #pragma unroll
      for (int k0 = 0; k0 < 128; k0 += 32) {
        bf16x8 fa[4], fb[2];
        #pragma unroll
        for (int f = 0; f < 4; ++f)
          fa[f] = *(const bf16x8*)(W2L + (cb * 128 + wr * 64 + f * 16 + lm) * 128 + k0 + lq * 8);
        #pragma unroll
        for (int g = 0; g < 2; ++g)
          fb[g] = *(const bf16x8*)(H_b + (h * 64 + wc * 32 + g * 16 + lm) * 128 + k0 + lq * 8);
        #pragma unroll
        for (int f = 0; f < 4; ++f)
          #pragma unroll
          for (int g = 0; g < 2; ++g)
            gacc[f][g] = __builtin_amdgcn_mfma_f32_16x16x32_bf16(fa[f], fb[g], gacc[f][g], 0, 0, 0);
      }
      #pragma unroll
      for (int f = 0; f < 4; ++f) {
        int n = cb * 32 + wr * 16 + f * 4 + lq;
        #pragma unroll
        for (int g = 0; g < 2; ++g) {
          int jl = wc * 32 + g * 16 + lm;          // j - h*64
          union { unsigned short h4[4]; uint2 v; } u;
          u.h4[0] = f2bf(gacc[f][g][0]); u.h4[1] = f2bf(gacc[f][g][1]);
          u.h4[2] = f2bf(gacc[f][g][2]); u.h4[3] = f2bf(gacc[f][g][3]);
          *(uint2*)(&Gs[n * GS_PITCH + jl * 4]) = u.v;
        }
      }
    }
    __syncthreads();

    // ---- phase 2: macc += Eb[:, h*256 .. h*256+256) @ Gs^T ----
    #pragma unroll
    for (int kt = 0; kt < 8; ++kt) {
      bf16x8 fa[4], fb[4];
      #pragma unroll
      for (int f = 0; f < 4; ++f)
        fa[f] = *(const bf16x8*)(E_b + (wr * 64 + f * 16 + lm) * 512 + h * 256 + kt * 32 + lq * 8);
      #pragma unroll
      for (int g = 0; g < 4; ++g)
        fb[g] = *(const bf16x8*)(&Gs[(wc * 64 + g * 16 + lm) * GS_PITCH + kt * 32 + lq * 8]);
      #pragma unroll
      for (int f = 0; f < 4; ++f)
        #pragma unroll
        for (int g = 0; g < 4; ++g)
          macc[f][g] = __builtin_amdgcn_mfma_f32_16x16x32_bf16(fa[f], fb[g], macc[f][g], 0, 0, 0);
    }
  }

  // ---- phase 1b: sacc = Hin @ SW (cols 512..639 of W2L) ----
  f32x4 sacc[4][4] = {};
  #pragma unroll
  for (int k0 = 0; k0 < 128; k0 += 32) {
    bf16x8 fa[4], fb[4];
    #pragma unroll
    for (int f = 0; f < 4; ++f)
      fa[f] = *(const bf16x8*)(H_b + (wr * 64 + f * 16 + lm) * 128 + k0 + lq * 8);
    #pragma unroll
    for (int g = 0; g < 4; ++g)
      fb[g] = *(const bf16x8*)(W2L + (512 + wc * 64 + g * 16 + lm) * 128 + k0 + lq * 8);
    #pragma unroll
    for (int f = 0; f < 4; ++f)
      #pragma unroll
      for (int g = 0; g < 4; ++g)
        sacc[f][g] = __builtin_amdgcn_mfma_f32_16x16x32_bf16(fa[f], fb[g], sacc[f][g], 0, 0, 0);
  }

  // ---- epilogue ----
  const float* dvb = Dv + b * 128;
  unsigned short* O_b = Hout + (size_t)b * 16384;
  #pragma unroll
  for (int f = 0; f < 4; ++f) {
    int i0 = wr * 64 + f * 16 + lq * 4;
    f32x4 d = *(const f32x4*)(dvb + i0);
    #pragma unroll
    for (int g = 0; g < 4; ++g) {
      int n = wc * 64 + g * 16 + lm;
      #pragma unroll
      for (int r = 0; r < 4; ++r) {
        float v = fmaf(macc[f][g][r], d[r], sacc[f][g][r]);
        O_b[(i0 + r) * 128 + n] = f2bf(1.0f / (1.0f + __expf(-v)));
      }
    }
  }
}

// ---------------------------------------------------------------------------
// MLP head on bf16 H
// ---------------------------------------------------------------------------
__global__ __launch_bounds__(256) void k_mlp(
    const unsigned short* __restrict__ H,   // [B*N][128] bf16
    const float* __restrict__ W1,  // [128][20]
    const float* __restrict__ b1,  // [20]
    const float* __restrict__ W2,  // [20]
    const float* __restrict__ b2,  // [1]
    float* __restrict__ sumOut)
{
  __shared__ float W1s[128 * 20];
  __shared__ float b1s[20], W2s[20];
  __shared__ float red[256];
  for (int i = threadIdx.x; i < 2560; i += 256) W1s[i] = W1[i];
  if (threadIdx.x < 20) { b1s[threadIdx.x] = b1[threadIdx.x]; W2s[threadIdx.x] = W2[threadIdx.x]; }
  __syncthreads();

  int row = blockIdx.x * 256 + threadIdx.x;
  float h[20];
  #pragma unroll
  for (int j = 0; j < 20; ++j) h[j] = b1s[j];
  const unsigned short* hr = H + (size_t)row * 128;
  for (int m8 = 0; m8 < 128; m8 += 8) {
    f32x4 pk = *(const f32x4*)(hr + m8);
    const unsigned short* us = (const unsigned short*)&pk;
    #pragma unroll
    for (int e = 0; e < 8; ++e) {
      float x = bf2f(us[e]);
      #pragma unroll
      for (int j = 0; j < 20; ++j) h[j] = fmaf(x, W1s[(m8 + e) * 20 + j], h[j]);
    }
  }
  float v = b2[0];
  #pragma unroll
  for (int j = 0; j < 20; ++j) {
    float t = h[j];
    t = fmaxf(t, 0.1f * t);
    v = fmaf(t, W2s[j], v);
  }
  float s = 1.0f / (1.0f + __expf(-v));

  red[threadIdx.x] = s;
  __syncthreads();
  #pragma unroll
  for (int off = 128; off > 0; off >>= 1) {
    if (threadIdx.x < off) red[threadIdx.x] += red[threadIdx.x + off];
    __syncthreads();
  }
  if (threadIdx.x == 0) atomicAdd(sumOut, red[0]);
}

__global__ void k_final(const float* __restrict__ sum, float* __restrict__ out) {
  out[0] = sum[0] * (1.0f / 65536.0f);
}

// ---------------------------------------------------------------------------
extern "C" void kernel_launch(void* const* d_in, const int* in_sizes, int n_in,
                              void* d_out, int out_size, void* d_ws, size_t ws_size,
                              hipStream_t stream) {
  const float* H   = (const float*)d_in[0];
  const float* E   = (const float*)d_in[1];
  const float* RW1 = (const float*)d_in[2];
  const float* SW1 = (const float*)d_in[3];
  const float* RW2 = (const float*)d_in[4];
  const float* SW2 = (const float*)d_in[5];
  const float* RW3 = (const float*)d_in[6];
  const float* SW3 = (const float*)d_in[7];
  const float* W1  = (const float*)d_in[8];
  const float* b1  = (const float*)d_in[9];
  const float* W2  = (const float*)d_in[10];
  const float* b2  = (const float*)d_in[11];
  float* out = (float*)d_out;

  char* w = (char*)d_ws;
  float*          wsD   = (float*)w;           w += (size_t)65536 * 4;
  unsigned short* wsEb  = (unsigned short*)w;  w += (size_t)33554432 * 2;
  unsigned short* wsHa  = (unsigned short*)w;  w += (size_t)8388608 * 2;
  unsigned short* wsHb  = (unsigned short*)w;  w += (size_t)8388608 * 2;
  unsigned short* wsW2  = (unsigned short*)w;  w += (size_t)3 * 81920 * 2;
  float*          wsSum = (float*)w;           w += 256;

  k_convE<<<BB * NN / 4, 256, 0, stream>>>(E, wsEb, wsD);
  k_convH<<<8388608 / (256 * 8), 256, 0, stream>>>(H, wsHa);
  k_buildW<<<320, 256, 0, stream>>>(RW1, SW1, wsW2);
  k_buildW<<<320, 256, 0, stream>>>(RW2, SW2, wsW2 + 81920);
  k_buildW<<<320, 256, 0, stream>>>(RW3, SW3, wsW2 + 163840);
  hipMemsetAsync(wsSum, 0, sizeof(float), stream);

  // fused layers (one block per graph)
  k_layer<<<BB, 256, 0, stream>>>(wsEb, wsHa, wsW2,          wsD, wsHb);
  k_layer<<<BB, 256, 0, stream>>>(wsEb, wsHb, wsW2 + 81920,  wsD, wsHa);
  k_layer<<<BB, 256, 0, stream>>>(wsEb, wsHa, wsW2 + 163840, wsD, wsHb);

  k_mlp<<<BB * NN / 256, 256, 0, stream>>>(wsHb, W1, b1, W2, b2, wsSum);
  k_final<<<1, 1, 0, stream>>>(wsSum, out);
}